// Round 1
// baseline (10781.236 us; speedup 1.0000x reference)
//
#include <hip/hip_runtime.h>
#include <hip/hip_bf16.h>
#include <math.h>

#define BB_ 64
#define TT_ 256
#define DD_ 512
#define HH_ 512
#define G4_ 2048
#define ODE_ 256

// ---------------------------------------------------------------------------
// Generic fp32 GEMM:  C[m,n] = act( scale * sum_k A[m,k]*W[n,k] + bias1[n] (+bias2[n]) )
// A: M x K row-major, W: N x K row-major (i.e. computes A @ W.T).
// Tiles: 128x128, BK=16, 256 threads, 8x8 per-thread micro-tile.
// Requires N % 128 == 0, K % 16 == 0. M may be ragged (clamped loads, guarded stores).
// ---------------------------------------------------------------------------
template <int ACT>  // 0 = none, 1 = tanh
__global__ __launch_bounds__(256) void gemm_bt(
    const float* __restrict__ A, const float* __restrict__ W,
    const float* __restrict__ bias1, const float* __restrict__ bias2,
    float* __restrict__ C, int M, int N, int K, float scale)
{
    const int BM = 128, BN = 128, BK = 16;
    __shared__ float As[BK][BM + 1];
    __shared__ float Ws[BK][BN + 1];
    const int tid = threadIdx.x;
    const int tx = tid & 15, ty = tid >> 4;
    const int m0 = blockIdx.y * BM, n0 = blockIdx.x * BN;

    float acc[8][8];
#pragma unroll
    for (int i = 0; i < 8; ++i)
#pragma unroll
        for (int j = 0; j < 8; ++j) acc[i][j] = 0.f;

    for (int k0 = 0; k0 < K; k0 += BK) {
#pragma unroll
        for (int i = 0; i < 2; ++i) {
            int lin = (i * 256 + tid) * 4;      // 0..4092
            int r = lin >> 4, c = lin & 15;     // r: 0..127, c in {0,4,8,12}
            int gm = m0 + r; if (gm > M - 1) gm = M - 1;
            float4 av = *(const float4*)(A + (size_t)gm * K + k0 + c);
            As[c + 0][r] = av.x; As[c + 1][r] = av.y;
            As[c + 2][r] = av.z; As[c + 3][r] = av.w;
            float4 wv = *(const float4*)(W + (size_t)(n0 + r) * K + k0 + c);
            Ws[c + 0][r] = wv.x; Ws[c + 1][r] = wv.y;
            Ws[c + 2][r] = wv.z; Ws[c + 3][r] = wv.w;
        }
        __syncthreads();
#pragma unroll
        for (int k = 0; k < BK; ++k) {
            float a[8], w[8];
#pragma unroll
            for (int i = 0; i < 8; ++i) a[i] = As[k][ty * 8 + i];
#pragma unroll
            for (int j = 0; j < 8; ++j) w[j] = Ws[k][tx * 8 + j];
#pragma unroll
            for (int i = 0; i < 8; ++i)
#pragma unroll
                for (int j = 0; j < 8; ++j) acc[i][j] += a[i] * w[j];
        }
        __syncthreads();
    }

#pragma unroll
    for (int j = 0; j < 8; ++j) {
        int n = n0 + tx * 8 + j;
        float bsum = bias1[n] + (bias2 ? bias2[n] : 0.f);
#pragma unroll
        for (int i = 0; i < 8; ++i) {
            int m = m0 + ty * 8 + i;
            if (m < M) {
                float v = acc[i][j] * scale + bsum;
                if (ACT == 1) v = tanhf(v);
                C[(size_t)m * N + n] = v;
            }
        }
    }
}

// ---------------------------------------------------------------------------
// One LSTM recurrence step (gate order i,f,g,o).
// g[b,j] = gx[b, t_orig, j] + sum_k h_in[b,k] * Whh[j,k]   (biases already in gx)
// Block: 256 threads covers 16 jh units x all 64 batches. Grid: 32 blocks.
// ---------------------------------------------------------------------------
__global__ __launch_bounds__(256) void lstm_step(
    const float* __restrict__ gx,     // (B, T, 4H)
    const float* __restrict__ Whh,    // (4H, H)
    const float* __restrict__ h_in,   // (B, H)
    float* __restrict__ h_out,        // (B, H)
    float* __restrict__ c,            // (B, H), updated in place
    float* __restrict__ hs_t,         // hs + t_step*B*H
    int t_step)
{
    __shared__ float ht[64][65];
    __shared__ float wt[64][65];
    const int tid = threadIdx.x;
    const int jh0 = blockIdx.x * 16;
    const int jh_l = tid >> 4;   // 0..15
    const int bg = tid & 15;     // 0..15 (4 batches each)
    const int t_orig = TT_ - 1 - t_step;

    float acc[4][4];
#pragma unroll
    for (int i = 0; i < 4; ++i)
#pragma unroll
        for (int j = 0; j < 4; ++j) acc[i][j] = 0.f;

    for (int kc = 0; kc < HH_; kc += 64) {
#pragma unroll
        for (int i = 0; i < 4; ++i) {
            int e = i * 256 + tid;          // 0..1023
            int r = e >> 4;                 // 0..63
            int k4 = (e & 15) * 4;          // 0..60
            float4 hv = *(const float4*)(h_in + (size_t)r * HH_ + kc + k4);
            ht[r][k4 + 0] = hv.x; ht[r][k4 + 1] = hv.y;
            ht[r][k4 + 2] = hv.z; ht[r][k4 + 3] = hv.w;
            int g = r >> 4, jl = r & 15;
            int j = g * 512 + jh0 + jl;
            float4 wv = *(const float4*)(Whh + (size_t)j * HH_ + kc + k4);
            wt[r][k4 + 0] = wv.x; wt[r][k4 + 1] = wv.y;
            wt[r][k4 + 2] = wv.z; wt[r][k4 + 3] = wv.w;
        }
        __syncthreads();
#pragma unroll 8
        for (int k = 0; k < 64; ++k) {
            float wv[4];
#pragma unroll
            for (int g = 0; g < 4; ++g) wv[g] = wt[g * 16 + jh_l][k];
#pragma unroll
            for (int bb = 0; bb < 4; ++bb) {
                float hv = ht[bg * 4 + bb][k];
#pragma unroll
                for (int g = 0; g < 4; ++g) acc[bb][g] += hv * wv[g];
            }
        }
        __syncthreads();
    }

    const int jh = jh0 + jh_l;
#pragma unroll
    for (int bb = 0; bb < 4; ++bb) {
        int b = bg * 4 + bb;
        const float* gxp = gx + ((size_t)b * TT_ + t_orig) * G4_;
        float gi = acc[bb][0] + gxp[jh];
        float gf = acc[bb][1] + gxp[512 + jh];
        float gg = acc[bb][2] + gxp[1024 + jh];
        float go = acc[bb][3] + gxp[1536 + jh];
        float si = 1.f / (1.f + expf(-gi));
        float sf = 1.f / (1.f + expf(-gf));
        float sg = tanhf(gg);
        float so = 1.f / (1.f + expf(-go));
        float cn = sf * c[b * HH_ + jh] + si * sg;
        float hn = so * tanhf(cn);
        c[b * HH_ + jh] = cn;
        h_out[b * HH_ + jh] = hn;
        hs_t[b * HH_ + jh] = hn;
    }
}

__global__ __launch_bounds__(256) void init_hc(
    const float* __restrict__ ah0, const float* __restrict__ ac0,
    float* __restrict__ h, float* __restrict__ c)
{
    int i = blockIdx.x * 256 + threadIdx.x;
    h[i] = ah0[i];
    c[i] = ac0[i];
}

// score[b,t] = dot(hs[T-1-t][b,:], Wa) + ba   (one wave per (b,t))
__global__ __launch_bounds__(256) void att_scores(
    const float* __restrict__ hs, const float* __restrict__ Wa,
    const float* __restrict__ ba, float* __restrict__ scores)
{
    int wid = (blockIdx.x * 256 + threadIdx.x) >> 6;  // 0..16383
    int lane = threadIdx.x & 63;
    int b = wid >> 8, t = wid & 255;
    int ts = TT_ - 1 - t;
    const float* hp = hs + ((size_t)ts * BB_ + b) * HH_;
    float sum = 0.f;
#pragma unroll
    for (int i = 0; i < 8; ++i) sum += hp[lane + i * 64] * Wa[lane + i * 64];
#pragma unroll
    for (int off = 32; off; off >>= 1) sum += __shfl_down(sum, off);
    if (lane == 0) scores[b * TT_ + t] = sum + ba[0];
}

// Per-batch softmax over T, then s[b,d] = sum_t alpha[b,t]*emb[b,t,d].
__global__ __launch_bounds__(256) void softmax_wsum(
    const float* __restrict__ scores, const float* __restrict__ emb,
    float* __restrict__ s)
{
    const int b = blockIdx.x;
    const int tid = threadIdx.x;
    __shared__ float sm[256];
    __shared__ float red[16];
    float v = scores[b * TT_ + tid];
    float m = v;
#pragma unroll
    for (int off = 32; off; off >>= 1) m = fmaxf(m, __shfl_xor(m, off));
    int wv = tid >> 6, ln = tid & 63;
    if (ln == 0) red[wv] = m;
    __syncthreads();
    float bm = fmaxf(fmaxf(red[0], red[1]), fmaxf(red[2], red[3]));
    float e = expf(v - bm);
    float ss = e;
#pragma unroll
    for (int off = 32; off; off >>= 1) ss += __shfl_xor(ss, off);
    if (ln == 0) red[8 + wv] = ss;
    __syncthreads();
    float tot = red[8] + red[9] + red[10] + red[11];
    sm[tid] = e / tot;
    __syncthreads();

    float acc0 = 0.f, acc1 = 0.f;
    const float* ep = emb + (size_t)b * TT_ * DD_;
    for (int t = 0; t < TT_; ++t) {
        float a = sm[t];
        acc0 += a * ep[t * DD_ + tid];
        acc1 += a * ep[t * DD_ + 256 + tid];
    }
    s[b * DD_ + tid] = acc0;
    s[b * DD_ + 256 + tid] = acc1;
}

__global__ __launch_bounds__(256) void mulvec(
    const float* __restrict__ a, const float* __restrict__ b,
    float* __restrict__ o, int n)
{
    int i = blockIdx.x * 256 + threadIdx.x;
    if (i < n) o[i] = a[i] * b[i];
}

extern "C" void kernel_launch(void* const* d_in, const int* in_sizes, int n_in,
                              void* d_out, int out_size, void* d_ws, size_t ws_size,
                              hipStream_t stream) {
    const float* x      = (const float*)d_in[0];
    const float* W_emb  = (const float*)d_in[1];
    const float* b_emb  = (const float*)d_in[2];
    const float* Wih_a  = (const float*)d_in[3];
    const float* Whh_a  = (const float*)d_in[4];
    const float* bih_a  = (const float*)d_in[5];
    const float* bhh_a  = (const float*)d_in[6];
    // d_in[7..10]: beta LSTM params — dead code in the reference, skipped.
    const float* W_aatt = (const float*)d_in[11];
    const float* b_aatt = (const float*)d_in[12];
    const float* W_batt = (const float*)d_in[13];
    const float* b_batt = (const float*)d_in[14];
    const float* W_mu   = (const float*)d_in[15];
    const float* b_mu   = (const float*)d_in[16];
    const float* W_sig  = (const float*)d_in[17];
    const float* b_sig  = (const float*)d_in[18];
    const float* ah0    = (const float*)d_in[19];
    const float* ac0    = (const float*)d_in[20];

    const size_t N_EMB = (size_t)BB_ * TT_ * DD_;   // 8,388,608
    const size_t N_GX  = (size_t)BB_ * TT_ * G4_;   // 33,554,432
    const size_t N_HS  = (size_t)TT_ * BB_ * HH_;   // 8,388,608
    const size_t N_BH  = (size_t)BB_ * HH_;         // 32,768

    size_t need_floats = N_EMB + N_GX + N_HS + 2 * N_BH + N_BH  // emb, gx, hs, hbuf(2), cbuf
                       + (size_t)BB_ * TT_                      // scores
                       + 3 * N_BH;                              // s, beta, var
    if (ws_size < need_floats * sizeof(float)) return;  // clean failure if scratch too small

    float* ws     = (float*)d_ws;
    float* emb    = ws;
    float* gx     = emb + N_EMB;
    float* hs     = gx + N_GX;
    float* hbuf   = hs + N_HS;          // 2 * B*H (double buffer)
    float* cbuf   = hbuf + 2 * N_BH;
    float* scores = cbuf + N_BH;
    float* svec   = scores + (size_t)BB_ * TT_;
    float* beta   = svec + N_BH;
    float* var    = beta + N_BH;

    float* out_mu  = (float*)d_out;
    float* out_sig = out_mu + (size_t)BB_ * ODE_;

    // 1. h0/c0 init
    init_hc<<<dim3(N_BH / 256), dim3(256), 0, stream>>>(ah0, ac0, hbuf, cbuf);

    // 2. emb = x @ W_emb.T + b_emb        (M=16384, N=512, K=512)
    gemm_bt<0><<<dim3(DD_ / 128, (BB_ * TT_) / 128), dim3(256), 0, stream>>>(
        x, W_emb, b_emb, nullptr, emb, BB_ * TT_, DD_, DD_, 1.f);

    // 3. gx = emb @ Wih_a.T + bih_a + bhh_a   (M=16384, N=2048, K=512)
    gemm_bt<0><<<dim3(G4_ / 128, (BB_ * TT_) / 128), dim3(256), 0, stream>>>(
        emb, Wih_a, bih_a, bhh_a, gx, BB_ * TT_, G4_, DD_, 1.f);

    // 4. recurrence (reversed time), 256 sequential steps
    for (int t = 0; t < TT_; ++t) {
        float* h_in  = hbuf + (size_t)(t & 1) * N_BH;
        float* h_out = hbuf + (size_t)((t + 1) & 1) * N_BH;
        lstm_step<<<dim3(32), dim3(256), 0, stream>>>(
            gx, Whh_a, h_in, h_out, cbuf, hs + (size_t)t * N_BH, t);
    }
    float* hT = hbuf;  // after 256 steps, parity lands back at buffer 0

    // 5. attention scores (one wave per (b,t))
    att_scores<<<dim3((BB_ * TT_) / 4), dim3(256), 0, stream>>>(hs, W_aatt, b_aatt, scores);

    // 6. softmax over T + weighted sum -> s[b,d]
    softmax_wsum<<<dim3(BB_), dim3(256), 0, stream>>>(scores, emb, svec);

    // 7. beta = tanh(hT @ W_batt.T + b_batt)  (M=64, N=512, K=512)
    gemm_bt<1><<<dim3(DD_ / 128, 1), dim3(256), 0, stream>>>(
        hT, W_batt, b_batt, nullptr, beta, BB_, DD_, DD_, 1.f);

    // 8. var = beta * s
    mulvec<<<dim3(N_BH / 256), dim3(256), 0, stream>>>(beta, svec, var, (int)N_BH);

    // 9. mu = (var/256) @ W_mu.T + b_mu ; sigma = var @ W_sig.T + b_sig
    gemm_bt<0><<<dim3(ODE_ / 128, 1), dim3(256), 0, stream>>>(
        var, W_mu, b_mu, nullptr, out_mu, BB_, ODE_, DD_, 1.f / 256.f);
    gemm_bt<0><<<dim3(ODE_ / 128, 1), dim3(256), 0, stream>>>(
        var, W_sig, b_sig, nullptr, out_sig, BB_, ODE_, DD_, 1.f);
}

// Round 2
// 7113.564 us; speedup vs baseline: 1.5156x; 1.5156x over previous
//
#include <hip/hip_runtime.h>
#include <hip/hip_bf16.h>
#include <math.h>

#define BB_ 64
#define TT_ 256
#define DD_ 512
#define HH_ 512
#define G4_ 2048
#define ODE_ 256

#define NBLK_ 128   // persistent LSTM grid: 32 j-blocks x 4 b-blocks

// ---------------------------------------------------------------------------
// Generic fp32 GEMM:  C[m,n] = act( scale * sum_k A[m,k]*W[n,k] + bias1[n] (+bias2[n]) )
// A: M x K row-major, W: N x K row-major (computes A @ W.T).
// ---------------------------------------------------------------------------
template <int ACT>  // 0 = none, 1 = tanh
__global__ __launch_bounds__(256) void gemm_bt(
    const float* __restrict__ A, const float* __restrict__ W,
    const float* __restrict__ bias1, const float* __restrict__ bias2,
    float* __restrict__ C, int M, int N, int K, float scale)
{
    const int BM = 128, BN = 128, BK = 16;
    __shared__ float As[BK][BM + 1];
    __shared__ float Ws[BK][BN + 1];
    const int tid = threadIdx.x;
    const int tx = tid & 15, ty = tid >> 4;
    const int m0 = blockIdx.y * BM, n0 = blockIdx.x * BN;

    float acc[8][8];
#pragma unroll
    for (int i = 0; i < 8; ++i)
#pragma unroll
        for (int j = 0; j < 8; ++j) acc[i][j] = 0.f;

    for (int k0 = 0; k0 < K; k0 += BK) {
#pragma unroll
        for (int i = 0; i < 2; ++i) {
            int lin = (i * 256 + tid) * 4;
            int r = lin >> 4, c = lin & 15;
            int gm = m0 + r; if (gm > M - 1) gm = M - 1;
            float4 av = *(const float4*)(A + (size_t)gm * K + k0 + c);
            As[c + 0][r] = av.x; As[c + 1][r] = av.y;
            As[c + 2][r] = av.z; As[c + 3][r] = av.w;
            float4 wv = *(const float4*)(W + (size_t)(n0 + r) * K + k0 + c);
            Ws[c + 0][r] = wv.x; Ws[c + 1][r] = wv.y;
            Ws[c + 2][r] = wv.z; Ws[c + 3][r] = wv.w;
        }
        __syncthreads();
#pragma unroll
        for (int k = 0; k < BK; ++k) {
            float a[8], w[8];
#pragma unroll
            for (int i = 0; i < 8; ++i) a[i] = As[k][ty * 8 + i];
#pragma unroll
            for (int j = 0; j < 8; ++j) w[j] = Ws[k][tx * 8 + j];
#pragma unroll
            for (int i = 0; i < 8; ++i)
#pragma unroll
                for (int j = 0; j < 8; ++j) acc[i][j] += a[i] * w[j];
        }
        __syncthreads();
    }

#pragma unroll
    for (int j = 0; j < 8; ++j) {
        int n = n0 + tx * 8 + j;
        float bsum = bias1[n] + (bias2 ? bias2[n] : 0.f);
#pragma unroll
        for (int i = 0; i < 8; ++i) {
            int m = m0 + ty * 8 + i;
            if (m < M) {
                float v = acc[i][j] * scale + bsum;
                if (ACT == 1) v = tanhf(v);
                C[(size_t)m * N + n] = v;
            }
        }
    }
}

// ---------------------------------------------------------------------------
// Persistent LSTM recurrence. 128 blocks x 256 threads, one kernel for all
// 256 time steps. Whh slice resident in LDS; c in registers; h exchanged via
// global in [k][b] (transposed) layout; grid barrier per step.
// Block: jb = blockIdx.x & 31 (16 jh units), bbg = blockIdx.x >> 5 (16 batches).
// Thread: jh_l = tid>>4 (0..15), bq = (tid>>2)&3 (4 batches), kq = tid&3 (k/4 split).
// ---------------------------------------------------------------------------
__global__ __launch_bounds__(256) void lstm_persist(
    const float* __restrict__ gx,     // (B, T, 4H) gate preacts from x (biases included)
    const float* __restrict__ Whh,    // (4H, H)
    const float* __restrict__ ac0,    // (B, H)
    float* __restrict__ hT0,          // (H, B) transposed h, buffer 0 (holds h0 at entry)
    float* __restrict__ hT1,          // (H, B) buffer 1
    float* __restrict__ hsT,          // (T, H, B) transposed per-step h
    unsigned* __restrict__ bar)       // grid barrier counter (zeroed)
{
    __shared__ float w4s[512 * 16 * 4];   // [k][jl_swz][gate]  128 KB
    __shared__ float gx_s[16 * 4 * 16];   // [b_local][gate][jl] 4 KB

    const int tid = threadIdx.x;
    const int jb  = blockIdx.x & 31;
    const int bbg = blockIdx.x >> 5;
    const int jh0 = jb * 16;
    const int b0  = bbg * 16;
    const int jh_l = tid >> 4;
    const int bq   = (tid >> 2) & 3;
    const int kq   = tid & 3;

    // ---- load Whh slice into LDS once: w4s[k][ (jl + (k>>7)*4)&15 ][g] ----
#pragma unroll
    for (int it = 0; it < 32; ++it) {
        int idx = it * 256 + tid;            // 0..8191
        int row = idx >> 7;                  // 0..63 = g*16+jl
        int c4  = (idx & 127) * 4;           // k base
        int g = row >> 4, jl = row & 15;
        float4 v = *(const float4*)(Whh + (size_t)(g * 512 + jh0 + jl) * 512 + c4);
        int sw = (jl + ((c4 >> 7) * 4)) & 15;   // c4..c4+3 share k>>7
        w4s[((c4 + 0) * 16 + sw) * 4 + g] = v.x;
        w4s[((c4 + 1) * 16 + sw) * 4 + g] = v.y;
        w4s[((c4 + 2) * 16 + sw) * 4 + g] = v.z;
        w4s[((c4 + 3) * 16 + sw) * 4 + g] = v.w;
    }

    // ---- c state in registers (kq==0 lanes own 4 b for their jh) ----
    const int jh = jh0 + jh_l;
    float creg[4];
    if (kq == 0) {
#pragma unroll
        for (int bb = 0; bb < 4; ++bb)
            creg[bb] = ac0[(size_t)(b0 + bq * 4 + bb) * HH_ + jh];
    }

    const int jl_sw = (jh_l + kq * 4) & 15;       // swizzled LDS column (const/thread)
    const float* wbase = w4s + ((size_t)kq * 128 * 16 + jl_sw) * 4;

    for (int t = 0; t < TT_; ++t) {
        const float* hin = (t & 1) ? hT1 : hT0;
        float* hout      = (t & 1) ? hT0 : hT1;
        const int t_orig = TT_ - 1 - t;

        // ---- stage this step's gx slice for the block (4 KB) ----
        {
            int lb = tid >> 4, g = (tid >> 2) & 3, q = tid & 3;
            const float* p = gx + ((size_t)(b0 + lb) * TT_ + t_orig) * G4_
                           + g * 512 + jh0 + q * 4;
            float4 v = *(const float4*)p;
            float* d = gx_s + ((lb * 4 + g) * 16 + q * 4);
            d[0] = v.x; d[1] = v.y; d[2] = v.z; d[3] = v.w;
        }
        __syncthreads();   // gx_s ready; also covers w4s on first iteration

        // ---- h @ Whh.T over this thread's k-range ----
        float acc[4][4];   // [bb][gate]
#pragma unroll
        for (int i = 0; i < 4; ++i)
#pragma unroll
            for (int j = 0; j < 4; ++j) acc[i][j] = 0.f;

        const float* hp = hin + (size_t)kq * 128 * 64 + b0 + bq * 4;
#pragma unroll 4
        for (int kk = 0; kk < 128; ++kk) {
            float4 hv = *(const float4*)(hp + (size_t)kk * 64);
            float4 wv = *(const float4*)(wbase + (size_t)kk * 64);
            acc[0][0] += hv.x * wv.x; acc[0][1] += hv.x * wv.y;
            acc[0][2] += hv.x * wv.z; acc[0][3] += hv.x * wv.w;
            acc[1][0] += hv.y * wv.x; acc[1][1] += hv.y * wv.y;
            acc[1][2] += hv.y * wv.z; acc[1][3] += hv.y * wv.w;
            acc[2][0] += hv.z * wv.x; acc[2][1] += hv.z * wv.y;
            acc[2][2] += hv.z * wv.z; acc[2][3] += hv.z * wv.w;
            acc[3][0] += hv.w * wv.x; acc[3][1] += hv.w * wv.y;
            acc[3][2] += hv.w * wv.z; acc[3][3] += hv.w * wv.w;
        }

        // ---- reduce over kq (lanes differing in tid bits 0-1, same wave) ----
#pragma unroll
        for (int i = 0; i < 4; ++i)
#pragma unroll
            for (int j = 0; j < 4; ++j) {
                acc[i][j] += __shfl_xor(acc[i][j], 1);
                acc[i][j] += __shfl_xor(acc[i][j], 2);
            }

        // ---- gates + state update (kq==0 lanes) ----
        if (kq == 0) {
            float hn[4];
#pragma unroll
            for (int bb = 0; bb < 4; ++bb) {
                int bl = bq * 4 + bb;
                float gi = acc[bb][0] + gx_s[(bl * 4 + 0) * 16 + jh_l];
                float gf = acc[bb][1] + gx_s[(bl * 4 + 1) * 16 + jh_l];
                float gg = acc[bb][2] + gx_s[(bl * 4 + 2) * 16 + jh_l];
                float go = acc[bb][3] + gx_s[(bl * 4 + 3) * 16 + jh_l];
                float si = 1.f / (1.f + expf(-gi));
                float sf = 1.f / (1.f + expf(-gf));
                float sg = tanhf(gg);
                float so = 1.f / (1.f + expf(-go));
                float cn = sf * creg[bb] + si * sg;
                creg[bb] = cn;
                hn[bb] = so * tanhf(cn);
            }
            float4 hv4 = make_float4(hn[0], hn[1], hn[2], hn[3]);
            *(float4*)(hout + (size_t)jh * 64 + b0 + bq * 4) = hv4;
            *(float4*)(hsT + ((size_t)t * 512 + jh) * 64 + b0 + bq * 4) = hv4;
        }

        // ---- grid barrier: publish hout, wait for everyone ----
        __syncthreads();
        if (tid == 0) {
            __hip_atomic_fetch_add(bar, 1u, __ATOMIC_ACQ_REL, __HIP_MEMORY_SCOPE_AGENT);
            unsigned target = (unsigned)(t + 1) * NBLK_;
            while (__hip_atomic_load(bar, __ATOMIC_ACQUIRE, __HIP_MEMORY_SCOPE_AGENT) < target)
                __builtin_amdgcn_s_sleep(2);
        }
        __syncthreads();
    }
}

// h0 -> transposed [jh][b]
__global__ __launch_bounds__(256) void h0_transpose(
    const float* __restrict__ ah0, float* __restrict__ hT0)
{
    int idx = blockIdx.x * 256 + threadIdx.x;   // 32768
    int b = idx >> 9, jh = idx & 511;
    hT0[jh * 64 + b] = ah0[idx];
}

// score[b][t_orig] = dot(hsT[ts][:][b], Wa) + ba,  ts = T-1-t_orig
__global__ __launch_bounds__(256) void att_scores_T(
    const float* __restrict__ hsT, const float* __restrict__ Wa,
    const float* __restrict__ ba, float* __restrict__ scores)
{
    int ts = blockIdx.x;
    int b = threadIdx.x & 63, part = threadIdx.x >> 6;
    const float* hp = hsT + (size_t)ts * 512 * 64;
    float s = 0.f;
#pragma unroll 8
    for (int jj = 0; jj < 128; ++jj) {
        int jh = part * 128 + jj;
        s += hp[(size_t)jh * 64 + b] * Wa[jh];
    }
    __shared__ float red[4][64];
    red[part][b] = s;
    __syncthreads();
    if (part == 0) {
        float tot = red[0][b] + red[1][b] + red[2][b] + red[3][b] + ba[0];
        scores[b * TT_ + (TT_ - 1 - ts)] = tot;
    }
}

// Per-batch softmax over T, then s[b,d] = sum_t alpha[b,t]*emb[b,t,d].
__global__ __launch_bounds__(256) void softmax_wsum(
    const float* __restrict__ scores, const float* __restrict__ emb,
    float* __restrict__ s)
{
    const int b = blockIdx.x;
    const int tid = threadIdx.x;
    __shared__ float sm[256];
    __shared__ float red[16];
    float v = scores[b * TT_ + tid];
    float m = v;
#pragma unroll
    for (int off = 32; off; off >>= 1) m = fmaxf(m, __shfl_xor(m, off));
    int wv = tid >> 6, ln = tid & 63;
    if (ln == 0) red[wv] = m;
    __syncthreads();
    float bm = fmaxf(fmaxf(red[0], red[1]), fmaxf(red[2], red[3]));
    float e = expf(v - bm);
    float ss = e;
#pragma unroll
    for (int off = 32; off; off >>= 1) ss += __shfl_xor(ss, off);
    if (ln == 0) red[8 + wv] = ss;
    __syncthreads();
    float tot = red[8] + red[9] + red[10] + red[11];
    sm[tid] = e / tot;
    __syncthreads();

    float acc0 = 0.f, acc1 = 0.f;
    const float* ep = emb + (size_t)b * TT_ * DD_;
    for (int t = 0; t < TT_; ++t) {
        float a = sm[t];
        acc0 += a * ep[t * DD_ + tid];
        acc1 += a * ep[t * DD_ + 256 + tid];
    }
    s[b * DD_ + tid] = acc0;
    s[b * DD_ + 256 + tid] = acc1;
}

// beta[b][d] = tanh( sum_jh hTT[jh][b] * Wb[d][jh] + bb )
__global__ __launch_bounds__(256) void beta_from_hT(
    const float* __restrict__ hTT, const float* __restrict__ Wb,
    const float* __restrict__ bbias, float* __restrict__ beta)
{
    int b = threadIdx.x & 63, w = threadIdx.x >> 6;
    int d = blockIdx.x * 4 + w;
    const float* wrow = Wb + (size_t)d * 512;
    float s = 0.f;
#pragma unroll 8
    for (int jh = 0; jh < 512; ++jh)
        s += hTT[(size_t)jh * 64 + b] * wrow[jh];
    beta[(size_t)b * 512 + d] = tanhf(s + bbias[d]);
}

__global__ __launch_bounds__(256) void mulvec(
    const float* __restrict__ a, const float* __restrict__ b,
    float* __restrict__ o, int n)
{
    int i = blockIdx.x * 256 + threadIdx.x;
    if (i < n) o[i] = a[i] * b[i];
}

extern "C" void kernel_launch(void* const* d_in, const int* in_sizes, int n_in,
                              void* d_out, int out_size, void* d_ws, size_t ws_size,
                              hipStream_t stream) {
    const float* x      = (const float*)d_in[0];
    const float* W_emb  = (const float*)d_in[1];
    const float* b_emb  = (const float*)d_in[2];
    const float* Wih_a  = (const float*)d_in[3];
    const float* Whh_a  = (const float*)d_in[4];
    const float* bih_a  = (const float*)d_in[5];
    const float* bhh_a  = (const float*)d_in[6];
    // d_in[7..10]: beta LSTM params — dead code in the reference, skipped.
    const float* W_aatt = (const float*)d_in[11];
    const float* b_aatt = (const float*)d_in[12];
    const float* W_batt = (const float*)d_in[13];
    const float* b_batt = (const float*)d_in[14];
    const float* W_mu   = (const float*)d_in[15];
    const float* b_mu   = (const float*)d_in[16];
    const float* W_sig  = (const float*)d_in[17];
    const float* b_sig  = (const float*)d_in[18];
    const float* ah0    = (const float*)d_in[19];
    const float* ac0    = (const float*)d_in[20];

    const size_t N_EMB = (size_t)BB_ * TT_ * DD_;   // 8,388,608
    const size_t N_GX  = (size_t)BB_ * TT_ * G4_;   // 33,554,432
    const size_t N_HS  = (size_t)TT_ * HH_ * BB_;   // 8,388,608
    const size_t N_BH  = (size_t)BB_ * HH_;         // 32,768

    size_t need_floats = 64 + N_EMB + N_GX + N_HS + 2 * N_BH
                       + (size_t)BB_ * TT_ + 3 * N_BH;
    if (ws_size < need_floats * sizeof(float)) return;

    float* ws     = (float*)d_ws;
    unsigned* bar = (unsigned*)d_ws;                // first 256 B = sync region
    float* emb    = ws + 64;
    float* gx     = emb + N_EMB;
    float* hsT    = gx + N_GX;
    float* hT0    = hsT + N_HS;
    float* hT1    = hT0 + N_BH;
    float* scores = hT1 + N_BH;
    float* svec   = scores + (size_t)BB_ * TT_;
    float* beta   = svec + N_BH;
    float* var    = beta + N_BH;

    float* out_mu  = (float*)d_out;
    float* out_sig = out_mu + (size_t)BB_ * ODE_;

    // 0. zero the grid-barrier counter (graph-capturable)
    hipMemsetAsync(d_ws, 0, 256, stream);

    // 1. h0 -> transposed layout
    h0_transpose<<<dim3(128), dim3(256), 0, stream>>>(ah0, hT0);

    // 2. emb = x @ W_emb.T + b_emb        (M=16384, N=512, K=512)
    gemm_bt<0><<<dim3(DD_ / 128, (BB_ * TT_) / 128), dim3(256), 0, stream>>>(
        x, W_emb, b_emb, nullptr, emb, BB_ * TT_, DD_, DD_, 1.f);

    // 3. gx = emb @ Wih_a.T + bih_a + bhh_a   (M=16384, N=2048, K=512)
    gemm_bt<0><<<dim3(G4_ / 128, (BB_ * TT_) / 128), dim3(256), 0, stream>>>(
        emb, Wih_a, bih_a, bhh_a, gx, BB_ * TT_, G4_, DD_, 1.f);

    // 4. full recurrence in ONE persistent kernel (128 blocks, grid barrier/step)
    lstm_persist<<<dim3(NBLK_), dim3(256), 0, stream>>>(
        gx, Whh_a, ac0, hT0, hT1, hsT, bar);
    // final h lands in hT0 (t=255 writes buffer 0)

    // 5. attention scores
    att_scores_T<<<dim3(TT_), dim3(256), 0, stream>>>(hsT, W_aatt, b_aatt, scores);

    // 6. softmax over T + weighted sum -> svec[b,d]
    softmax_wsum<<<dim3(BB_), dim3(256), 0, stream>>>(scores, emb, svec);

    // 7. beta = tanh(hT @ W_batt.T + b_batt)   (reads transposed hT0)
    beta_from_hT<<<dim3(DD_ / 4), dim3(256), 0, stream>>>(hT0, W_batt, b_batt, beta);

    // 8. var = beta * svec
    mulvec<<<dim3(N_BH / 256), dim3(256), 0, stream>>>(beta, svec, var, (int)N_BH);

    // 9. mu = (var/256) @ W_mu.T + b_mu ; sigma = var @ W_sig.T + b_sig
    gemm_bt<0><<<dim3(ODE_ / 128, 1), dim3(256), 0, stream>>>(
        var, W_mu, b_mu, nullptr, out_mu, BB_, ODE_, DD_, 1.f / 256.f);
    gemm_bt<0><<<dim3(ODE_ / 128, 1), dim3(256), 0, stream>>>(
        var, W_sig, b_sig, nullptr, out_sig, BB_, ODE_, DD_, 1.f);
}

// Round 3
// 6544.448 us; speedup vs baseline: 1.6474x; 1.0870x over previous
//
#include <hip/hip_runtime.h>
#include <hip/hip_bf16.h>
#include <math.h>

#define BB_ 64
#define TT_ 256
#define DD_ 512
#define HH_ 512
#define G4_ 2048
#define ODE_ 256

#define NBLK_ 256   // persistent LSTM grid: 64 j-blocks x 4 b-blocks

// ---------------------------------------------------------------------------
// Generic fp32 GEMM:  C[m,n] = act( scale * sum_k A[m,k]*W[n,k] + bias1[n] (+bias2[n]) )
// A: M x K row-major, W: N x K row-major (computes A @ W.T).
// LDS rows padded to 132 floats (16B-aligned) so 8-float fragment reads
// vectorize to 2x ds_read_b128.
// ---------------------------------------------------------------------------
template <int ACT>  // 0 = none, 1 = tanh
__global__ __launch_bounds__(256) void gemm_bt(
    const float* __restrict__ A, const float* __restrict__ W,
    const float* __restrict__ bias1, const float* __restrict__ bias2,
    float* __restrict__ C, int M, int N, int K, float scale)
{
    const int BM = 128, BN = 128, BK = 16;
    __shared__ float As[BK][BM + 4];
    __shared__ float Ws[BK][BN + 4];
    const int tid = threadIdx.x;
    const int tx = tid & 15, ty = tid >> 4;
    const int m0 = blockIdx.y * BM, n0 = blockIdx.x * BN;

    float acc[8][8];
#pragma unroll
    for (int i = 0; i < 8; ++i)
#pragma unroll
        for (int j = 0; j < 8; ++j) acc[i][j] = 0.f;

    for (int k0 = 0; k0 < K; k0 += BK) {
#pragma unroll
        for (int i = 0; i < 2; ++i) {
            int lin = (i * 256 + tid) * 4;
            int r = lin >> 4, c = lin & 15;
            int gm = m0 + r; if (gm > M - 1) gm = M - 1;
            float4 av = *(const float4*)(A + (size_t)gm * K + k0 + c);
            As[c + 0][r] = av.x; As[c + 1][r] = av.y;
            As[c + 2][r] = av.z; As[c + 3][r] = av.w;
            float4 wv = *(const float4*)(W + (size_t)(n0 + r) * K + k0 + c);
            Ws[c + 0][r] = wv.x; Ws[c + 1][r] = wv.y;
            Ws[c + 2][r] = wv.z; Ws[c + 3][r] = wv.w;
        }
        __syncthreads();
#pragma unroll
        for (int k = 0; k < BK; ++k) {
            float a[8], w[8];
#pragma unroll
            for (int i = 0; i < 8; ++i) a[i] = As[k][ty * 8 + i];
#pragma unroll
            for (int j = 0; j < 8; ++j) w[j] = Ws[k][tx * 8 + j];
#pragma unroll
            for (int i = 0; i < 8; ++i)
#pragma unroll
                for (int j = 0; j < 8; ++j) acc[i][j] += a[i] * w[j];
        }
        __syncthreads();
    }

#pragma unroll
    for (int j = 0; j < 8; ++j) {
        int n = n0 + tx * 8 + j;
        float bsum = bias1[n] + (bias2 ? bias2[n] : 0.f);
#pragma unroll
        for (int i = 0; i < 8; ++i) {
            int m = m0 + ty * 8 + i;
            if (m < M) {
                float v = acc[i][j] * scale + bsum;
                if (ACT == 1) v = tanhf(v);
                C[(size_t)m * N + n] = v;
            }
        }
    }
}

// ---------------------------------------------------------------------------
// Persistent LSTM recurrence. 256 blocks x 256 threads (all CUs).
// Block: jb = blockIdx.x >> 2 (8 jh units), bg = blockIdx.x & 3 (16 batches).
// Thread: kq = tid & 15 (16-way k-split, 32 k each), bq = (tid>>4)&1 (8 b each),
//         jh_l = tid >> 5 (0..7).
// Whh slice (64 KB) resident in LDS (bank-swizzled); c in registers; h
// exchanged via global [k][b] layout; distributed flag barrier per step
// (one release-store per block to its own cache line, wave0 polls all).
// ---------------------------------------------------------------------------
__global__ __launch_bounds__(256) void lstm_persist(
    const float* __restrict__ gx,     // (B, T, 4H) gate preacts from x (biases included)
    const float* __restrict__ Whh,    // (4H, H)
    const float* __restrict__ ac0,    // (B, H)
    float* __restrict__ hT0,          // (H, B) transposed h, buffer 0 (holds h0 at entry)
    float* __restrict__ hT1,          // (H, B) buffer 1
    float* __restrict__ hsT,          // (T, H, B) transposed per-step h
    unsigned* __restrict__ arr)       // NBLK_ arrival slots, stride 32 u32 (128B)
{
    __shared__ float w4s[512 * 8 * 4];    // [k][jl_swz][gate]  64 KB
    __shared__ float gx_s[16 * 33];       // [b_local][g*8+jl], padded

    const int tid = threadIdx.x;
    const int jb = blockIdx.x >> 2;
    const int bg = blockIdx.x & 3;
    const int jh0 = jb * 8;
    const int b0  = bg * 16;
    const int kq   = tid & 15;
    const int bq   = (tid >> 4) & 1;
    const int jh_l = tid >> 5;

    // ---- load Whh slice into LDS once: w4s[k][(jl + (k>>5)) & 7][g] ----
#pragma unroll
    for (int it = 0; it < 16; ++it) {
        int idx = it * 256 + tid;            // 0..4095
        int row = idx >> 7;                  // 0..31 = g*8 + jl
        int g = row >> 3, jl = row & 7;
        int c4 = (idx & 127) * 4;            // k base (c4..c4+3 share k>>5)
        float4 v = *(const float4*)(Whh + (size_t)(g * 512 + jh0 + jl) * 512 + c4);
        int sw = (jl + (c4 >> 5)) & 7;
        w4s[((c4 + 0) * 8 + sw) * 4 + g] = v.x;
        w4s[((c4 + 1) * 8 + sw) * 4 + g] = v.y;
        w4s[((c4 + 2) * 8 + sw) * 4 + g] = v.z;
        w4s[((c4 + 3) * 8 + sw) * 4 + g] = v.w;
    }

    // ---- per-thread state: active lanes (kq<8) own one (b, jh) pair ----
    const int jh = jh0 + jh_l;
    const int b  = b0 + bq * 8 + kq;       // valid when kq < 8
    float creg = 0.f;
    if (kq < 8) creg = ac0[(size_t)b * HH_ + jh];

    // gx stage mapping: thread (lb, g, jl2) loads float2
    const int g_lb  = tid >> 4;            // 0..15 local batch
    const int g_g   = (tid >> 2) & 3;      // gate
    const int g_jl2 = (tid & 3) * 2;       // jl pair
    const float* gsrc = gx + (size_t)(b0 + g_lb) * TT_ * G4_ + g_g * 512 + jh0 + g_jl2;

    // prefetch gx for t = 0 (t_orig = 255)
    float2 gxreg = *(const float2*)(gsrc + (size_t)255 * G4_);

    const float* wp = w4s + ((size_t)(kq * 32) * 8 + ((jh_l + kq) & 7)) * 4;

    for (int t = 0; t < TT_; ++t) {
        const float* hin = (t & 1) ? hT1 : hT0;
        float* hout      = (t & 1) ? hT0 : hT1;

        // publish this step's gx slice to LDS
        gx_s[g_lb * 33 + g_g * 8 + g_jl2]     = gxreg.x;
        gx_s[g_lb * 33 + g_g * 8 + g_jl2 + 1] = gxreg.y;
        __syncthreads();     // gx_s ready (covers w4s init on first iter)

        // prefetch next step's gx (latency hides under compute)
        if (t + 1 < TT_)
            gxreg = *(const float2*)(gsrc + (size_t)(TT_ - 2 - t) * G4_);

        // ---- h @ Whh.T over this thread's k-range (32 k, 8 b, 4 gates) ----
        float acc[8][4];
#pragma unroll
        for (int i = 0; i < 8; ++i)
#pragma unroll
            for (int j = 0; j < 4; ++j) acc[i][j] = 0.f;

        const float* hp = hin + (size_t)kq * 32 * 64 + b0 + bq * 8;
#pragma unroll 8
        for (int kk = 0; kk < 32; ++kk) {
            float4 wv = *(const float4*)(wp + (size_t)kk * 32);
            float4 ha = *(const float4*)(hp + (size_t)kk * 64);
            float4 hb = *(const float4*)(hp + (size_t)kk * 64 + 4);
            float hv[8] = {ha.x, ha.y, ha.z, ha.w, hb.x, hb.y, hb.z, hb.w};
#pragma unroll
            for (int bb = 0; bb < 8; ++bb) {
                acc[bb][0] += hv[bb] * wv.x;
                acc[bb][1] += hv[bb] * wv.y;
                acc[bb][2] += hv[bb] * wv.z;
                acc[bb][3] += hv[bb] * wv.w;
            }
        }

        // ---- butterfly reduce over kq (tid bits 0..3) -> full sum in all lanes ----
#pragma unroll
        for (int m = 1; m <= 8; m <<= 1)
#pragma unroll
            for (int bb = 0; bb < 8; ++bb)
#pragma unroll
                for (int g = 0; g < 4; ++g)
                    acc[bb][g] += __shfl_xor(acc[bb][g], m);

        // ---- gates + state update (lanes kq<8; lane kq owns batch index kq) ----
        if (kq < 8) {
            float gi = 0.f, gf = 0.f, gg = 0.f, go = 0.f;
#pragma unroll
            for (int bb = 0; bb < 8; ++bb)
                if (kq == bb) { gi = acc[bb][0]; gf = acc[bb][1];
                                gg = acc[bb][2]; go = acc[bb][3]; }
            int bl = bq * 8 + kq;
            gi += gx_s[bl * 33 + 0 * 8 + jh_l];
            gf += gx_s[bl * 33 + 1 * 8 + jh_l];
            gg += gx_s[bl * 33 + 2 * 8 + jh_l];
            go += gx_s[bl * 33 + 3 * 8 + jh_l];
            float si = 1.f / (1.f + expf(-gi));
            float sf = 1.f / (1.f + expf(-gf));
            float sg = tanhf(gg);
            float so = 1.f / (1.f + expf(-go));
            creg = sf * creg + si * sg;
            float hn = so * tanhf(creg);
            hout[(size_t)jh * 64 + b] = hn;
            hsT[((size_t)t * 512 + jh) * 64 + b] = hn;
        }

        // ---- distributed grid barrier ----
        __syncthreads();
        if (tid == 0)
            __hip_atomic_store(&arr[(size_t)blockIdx.x * 32], (unsigned)(t + 1),
                               __ATOMIC_RELEASE, __HIP_MEMORY_SCOPE_AGENT);
        unsigned tgt = (unsigned)(t + 1);
        if (tid < 64) {
#pragma unroll
            for (int q = 0; q < 4; ++q) {
                while (__hip_atomic_load(&arr[(size_t)(tid * 4 + q) * 32],
                                         __ATOMIC_ACQUIRE, __HIP_MEMORY_SCOPE_AGENT) < tgt)
                    __builtin_amdgcn_s_sleep(1);
            }
        }
        __syncthreads();
    }
}

// h0 -> transposed [jh][b]
__global__ __launch_bounds__(256) void h0_transpose(
    const float* __restrict__ ah0, float* __restrict__ hT0)
{
    int idx = blockIdx.x * 256 + threadIdx.x;   // 32768
    int b = idx >> 9, jh = idx & 511;
    hT0[jh * 64 + b] = ah0[idx];
}

// score[b][t_orig] = dot(hsT[ts][:][b], Wa) + ba,  ts = T-1-t_orig
__global__ __launch_bounds__(256) void att_scores_T(
    const float* __restrict__ hsT, const float* __restrict__ Wa,
    const float* __restrict__ ba, float* __restrict__ scores)
{
    int ts = blockIdx.x;
    int b = threadIdx.x & 63, part = threadIdx.x >> 6;
    const float* hp = hsT + (size_t)ts * 512 * 64;
    float s = 0.f;
#pragma unroll 8
    for (int jj = 0; jj < 128; ++jj) {
        int jh = part * 128 + jj;
        s += hp[(size_t)jh * 64 + b] * Wa[jh];
    }
    __shared__ float red[4][64];
    red[part][b] = s;
    __syncthreads();
    if (part == 0) {
        float tot = red[0][b] + red[1][b] + red[2][b] + red[3][b] + ba[0];
        scores[b * TT_ + (TT_ - 1 - ts)] = tot;
    }
}

// Per-batch softmax over T, then s[b,d] = sum_t alpha[b,t]*emb[b,t,d].
__global__ __launch_bounds__(256) void softmax_wsum(
    const float* __restrict__ scores, const float* __restrict__ emb,
    float* __restrict__ s)
{
    const int b = blockIdx.x;
    const int tid = threadIdx.x;
    __shared__ float sm[256];
    __shared__ float red[16];
    float v = scores[b * TT_ + tid];
    float m = v;
#pragma unroll
    for (int off = 32; off; off >>= 1) m = fmaxf(m, __shfl_xor(m, off));
    int wv = tid >> 6, ln = tid & 63;
    if (ln == 0) red[wv] = m;
    __syncthreads();
    float bm = fmaxf(fmaxf(red[0], red[1]), fmaxf(red[2], red[3]));
    float e = expf(v - bm);
    float ss = e;
#pragma unroll
    for (int off = 32; off; off >>= 1) ss += __shfl_xor(ss, off);
    if (ln == 0) red[8 + wv] = ss;
    __syncthreads();
    float tot = red[8] + red[9] + red[10] + red[11];
    sm[tid] = e / tot;
    __syncthreads();

    float acc0 = 0.f, acc1 = 0.f;
    const float* ep = emb + (size_t)b * TT_ * DD_;
    for (int t = 0; t < TT_; ++t) {
        float a = sm[t];
        acc0 += a * ep[t * DD_ + tid];
        acc1 += a * ep[t * DD_ + 256 + tid];
    }
    s[b * DD_ + tid] = acc0;
    s[b * DD_ + 256 + tid] = acc1;
}

// beta[b][d] = tanh( sum_jh hTT[jh][b] * Wb[d][jh] + bb )
__global__ __launch_bounds__(256) void beta_from_hT(
    const float* __restrict__ hTT, const float* __restrict__ Wb,
    const float* __restrict__ bbias, float* __restrict__ beta)
{
    int b = threadIdx.x & 63, w = threadIdx.x >> 6;
    int d = blockIdx.x * 4 + w;
    const float* wrow = Wb + (size_t)d * 512;
    float s = 0.f;
#pragma unroll 8
    for (int jh = 0; jh < 512; ++jh)
        s += hTT[(size_t)jh * 64 + b] * wrow[jh];
    beta[(size_t)b * 512 + d] = tanhf(s + bbias[d]);
}

__global__ __launch_bounds__(256) void mulvec(
    const float* __restrict__ a, const float* __restrict__ b,
    float* __restrict__ o, int n)
{
    int i = blockIdx.x * 256 + threadIdx.x;
    if (i < n) o[i] = a[i] * b[i];
}

extern "C" void kernel_launch(void* const* d_in, const int* in_sizes, int n_in,
                              void* d_out, int out_size, void* d_ws, size_t ws_size,
                              hipStream_t stream) {
    const float* x      = (const float*)d_in[0];
    const float* W_emb  = (const float*)d_in[1];
    const float* b_emb  = (const float*)d_in[2];
    const float* Wih_a  = (const float*)d_in[3];
    const float* Whh_a  = (const float*)d_in[4];
    const float* bih_a  = (const float*)d_in[5];
    const float* bhh_a  = (const float*)d_in[6];
    // d_in[7..10]: beta LSTM params — dead code in the reference, skipped.
    const float* W_aatt = (const float*)d_in[11];
    const float* b_aatt = (const float*)d_in[12];
    const float* W_batt = (const float*)d_in[13];
    const float* b_batt = (const float*)d_in[14];
    const float* W_mu   = (const float*)d_in[15];
    const float* b_mu   = (const float*)d_in[16];
    const float* W_sig  = (const float*)d_in[17];
    const float* b_sig  = (const float*)d_in[18];
    const float* ah0    = (const float*)d_in[19];
    const float* ac0    = (const float*)d_in[20];

    const size_t N_EMB = (size_t)BB_ * TT_ * DD_;   // 8,388,608
    const size_t N_GX  = (size_t)BB_ * TT_ * G4_;   // 33,554,432
    const size_t N_HS  = (size_t)TT_ * HH_ * BB_;   // 8,388,608
    const size_t N_BH  = (size_t)BB_ * HH_;         // 32,768
    const size_t N_BAR = 8192;                      // 32 KB barrier region

    size_t need_floats = N_BAR + N_EMB + N_GX + N_HS + 2 * N_BH
                       + (size_t)BB_ * TT_ + 3 * N_BH;
    if (ws_size < need_floats * sizeof(float)) return;

    float* ws     = (float*)d_ws;
    unsigned* arr = (unsigned*)d_ws;                // barrier slots
    float* emb    = ws + N_BAR;
    float* gx     = emb + N_EMB;
    float* hsT    = gx + N_GX;
    float* hT0    = hsT + N_HS;
    float* hT1    = hT0 + N_BH;
    float* scores = hT1 + N_BH;
    float* svec   = scores + (size_t)BB_ * TT_;
    float* beta   = svec + N_BH;
    float* var    = beta + N_BH;

    float* out_mu  = (float*)d_out;
    float* out_sig = out_mu + (size_t)BB_ * ODE_;

    // 0. zero the barrier slots (graph-capturable)
    hipMemsetAsync(d_ws, 0, N_BAR * sizeof(float), stream);

    // 1. h0 -> transposed layout
    h0_transpose<<<dim3(128), dim3(256), 0, stream>>>(ah0, hT0);

    // 2. emb = x @ W_emb.T + b_emb        (M=16384, N=512, K=512)
    gemm_bt<0><<<dim3(DD_ / 128, (BB_ * TT_) / 128), dim3(256), 0, stream>>>(
        x, W_emb, b_emb, nullptr, emb, BB_ * TT_, DD_, DD_, 1.f);

    // 3. gx = emb @ Wih_a.T + bih_a + bhh_a   (M=16384, N=2048, K=512)
    gemm_bt<0><<<dim3(G4_ / 128, (BB_ * TT_) / 128), dim3(256), 0, stream>>>(
        emb, Wih_a, bih_a, bhh_a, gx, BB_ * TT_, G4_, DD_, 1.f);

    // 4. full recurrence in ONE persistent kernel (256 blocks, flag barrier/step)
    lstm_persist<<<dim3(NBLK_), dim3(256), 0, stream>>>(
        gx, Whh_a, ac0, hT0, hT1, hsT, arr);
    // final h lands in hT0 (t=255 writes buffer 0)

    // 5. attention scores
    att_scores_T<<<dim3(TT_), dim3(256), 0, stream>>>(hsT, W_aatt, b_aatt, scores);

    // 6. softmax over T + weighted sum -> svec[b,d]
    softmax_wsum<<<dim3(BB_), dim3(256), 0, stream>>>(scores, emb, svec);

    // 7. beta = tanh(hT @ W_batt.T + b_batt)   (reads transposed hT0)
    beta_from_hT<<<dim3(DD_ / 4), dim3(256), 0, stream>>>(hT0, W_batt, b_batt, beta);

    // 8. var = beta * svec
    mulvec<<<dim3(N_BH / 256), dim3(256), 0, stream>>>(beta, svec, var, (int)N_BH);

    // 9. mu = (var/256) @ W_mu.T + b_mu ; sigma = var @ W_sig.T + b_sig
    gemm_bt<0><<<dim3(ODE_ / 128, 1), dim3(256), 0, stream>>>(
        var, W_mu, b_mu, nullptr, out_mu, BB_, ODE_, DD_, 1.f / 256.f);
    gemm_bt<0><<<dim3(ODE_ / 128, 1), dim3(256), 0, stream>>>(
        var, W_sig, b_sig, nullptr, out_sig, BB_, ODE_, DD_, 1.f);
}

// Round 4
// 5160.136 us; speedup vs baseline: 2.0893x; 1.2683x over previous
//
#include <hip/hip_runtime.h>
#include <hip/hip_bf16.h>
#include <math.h>

#define BB_ 64
#define TT_ 256
#define DD_ 512
#define HH_ 512
#define G4_ 2048
#define ODE_ 256

#define NBLK_ 256   // persistent LSTM grid: 64 j-blocks x 4 b-blocks

// Coherent (cross-XCD) 8-byte load/store: RELAXED AGENT atomics compile to
// global_load/store_dwordx2 with sc1 -> bypass stale per-XCD L2, no cache-wide
// maintenance (unlike acquire/release which emit buffer_inv / wbl2).
__device__ __forceinline__ float2 cohload2(const float* p) {
    unsigned long long u = __hip_atomic_load(
        (unsigned long long*)p, __ATOMIC_RELAXED, __HIP_MEMORY_SCOPE_AGENT);
    union { unsigned long long u; float2 f; } c; c.u = u;
    return c.f;
}
__device__ __forceinline__ void cohstore2(float* p, float a, float b) {
    union { unsigned long long u; float2 f; } c; c.f = make_float2(a, b);
    __hip_atomic_store((unsigned long long*)p, c.u,
                       __ATOMIC_RELAXED, __HIP_MEMORY_SCOPE_AGENT);
}

// ---------------------------------------------------------------------------
// Generic fp32 GEMM:  C[m,n] = act( scale * sum_k A[m,k]*W[n,k] + bias1[n] (+bias2[n]) )
// A: M x K row-major, W: N x K row-major (computes A @ W.T).
// ---------------------------------------------------------------------------
template <int ACT>  // 0 = none, 1 = tanh
__global__ __launch_bounds__(256) void gemm_bt(
    const float* __restrict__ A, const float* __restrict__ W,
    const float* __restrict__ bias1, const float* __restrict__ bias2,
    float* __restrict__ C, int M, int N, int K, float scale)
{
    const int BM = 128, BN = 128, BK = 16;
    __shared__ float As[BK][BM + 4];
    __shared__ float Ws[BK][BN + 4];
    const int tid = threadIdx.x;
    const int tx = tid & 15, ty = tid >> 4;
    const int m0 = blockIdx.y * BM, n0 = blockIdx.x * BN;

    float acc[8][8];
#pragma unroll
    for (int i = 0; i < 8; ++i)
#pragma unroll
        for (int j = 0; j < 8; ++j) acc[i][j] = 0.f;

    for (int k0 = 0; k0 < K; k0 += BK) {
#pragma unroll
        for (int i = 0; i < 2; ++i) {
            int lin = (i * 256 + tid) * 4;
            int r = lin >> 4, c = lin & 15;
            int gm = m0 + r; if (gm > M - 1) gm = M - 1;
            float4 av = *(const float4*)(A + (size_t)gm * K + k0 + c);
            As[c + 0][r] = av.x; As[c + 1][r] = av.y;
            As[c + 2][r] = av.z; As[c + 3][r] = av.w;
            float4 wv = *(const float4*)(W + (size_t)(n0 + r) * K + k0 + c);
            Ws[c + 0][r] = wv.x; Ws[c + 1][r] = wv.y;
            Ws[c + 2][r] = wv.z; Ws[c + 3][r] = wv.w;
        }
        __syncthreads();
#pragma unroll
        for (int k = 0; k < BK; ++k) {
            float a[8], w[8];
#pragma unroll
            for (int i = 0; i < 8; ++i) a[i] = As[k][ty * 8 + i];
#pragma unroll
            for (int j = 0; j < 8; ++j) w[j] = Ws[k][tx * 8 + j];
#pragma unroll
            for (int i = 0; i < 8; ++i)
#pragma unroll
                for (int j = 0; j < 8; ++j) acc[i][j] += a[i] * w[j];
        }
        __syncthreads();
    }

#pragma unroll
    for (int j = 0; j < 8; ++j) {
        int n = n0 + tx * 8 + j;
        float bsum = bias1[n] + (bias2 ? bias2[n] : 0.f);
#pragma unroll
        for (int i = 0; i < 8; ++i) {
            int m = m0 + ty * 8 + i;
            if (m < M) {
                float v = acc[i][j] * scale + bsum;
                if (ACT == 1) v = tanhf(v);
                C[(size_t)m * N + n] = v;
            }
        }
    }
}

// ---------------------------------------------------------------------------
// Persistent LSTM recurrence. 256 blocks x 256 threads (all CUs).
// Block: jb = blockIdx.x >> 2 (8 jh units), bg = blockIdx.x & 3 (16 batches).
// Thread: kq = tid & 15 (16-way k-split), bq = (tid>>4)&1, jh_l = tid >> 5.
// Whh slice (64 KB) resident in LDS; c in registers; h exchanged through the
// Infinity Cache via relaxed sc1 atomics (no cache-maintenance ops); flag
// barrier with relaxed store + relaxed poll (ordering via __syncthreads'
// vmcnt drain + sc1 write-through visibility).
// ---------------------------------------------------------------------------
__global__ __launch_bounds__(256) void lstm_persist(
    const float* __restrict__ gx,     // (B, T, 4H) gate preacts from x (biases included)
    const float* __restrict__ Whh,    // (4H, H)
    const float* __restrict__ ac0,    // (B, H)
    float* __restrict__ hT0,          // (H, B) transposed h, buffer 0 (holds h0 at entry)
    float* __restrict__ hT1,          // (H, B) buffer 1
    float* __restrict__ hsT,          // (T, H, B) transposed per-step h
    unsigned* __restrict__ arr)       // NBLK_ arrival slots, stride 32 u32 (128B)
{
    __shared__ float w4s[512 * 8 * 4];    // [k][jl_swz][gate]  64 KB
    __shared__ float gx_s[16 * 33];       // [b_local][g*8+jl], padded

    const int tid = threadIdx.x;
    const int jb = blockIdx.x >> 2;
    const int bg = blockIdx.x & 3;
    const int jh0 = jb * 8;
    const int b0  = bg * 16;
    const int kq   = tid & 15;
    const int bq   = (tid >> 4) & 1;
    const int jh_l = tid >> 5;

    // ---- load Whh slice into LDS once: w4s[k][(jl + (k>>5)) & 7][g] ----
#pragma unroll
    for (int it = 0; it < 16; ++it) {
        int idx = it * 256 + tid;            // 0..4095
        int row = idx >> 7;                  // 0..31 = g*8 + jl
        int g = row >> 3, jl = row & 7;
        int c4 = (idx & 127) * 4;            // k base (c4..c4+3 share k>>5)
        float4 v = *(const float4*)(Whh + (size_t)(g * 512 + jh0 + jl) * 512 + c4);
        int sw = (jl + (c4 >> 5)) & 7;
        w4s[((c4 + 0) * 8 + sw) * 4 + g] = v.x;
        w4s[((c4 + 1) * 8 + sw) * 4 + g] = v.y;
        w4s[((c4 + 2) * 8 + sw) * 4 + g] = v.z;
        w4s[((c4 + 3) * 8 + sw) * 4 + g] = v.w;
    }

    // ---- per-thread state: active lanes (kq<8) own one (b, jh) pair ----
    const int jh = jh0 + jh_l;
    const int b  = b0 + bq * 8 + kq;       // valid when kq < 8
    float creg = 0.f;
    if (kq < 8) creg = ac0[(size_t)b * HH_ + jh];

    // gx stage mapping: thread (lb, g, jl2) loads float2
    const int g_lb  = tid >> 4;            // 0..15 local batch
    const int g_g   = (tid >> 2) & 3;      // gate
    const int g_jl2 = (tid & 3) * 2;       // jl pair
    const float* gsrc = gx + (size_t)(b0 + g_lb) * TT_ * G4_ + g_g * 512 + jh0 + g_jl2;

    // prefetch gx for t = 0 (t_orig = 255)
    float2 gxreg = *(const float2*)(gsrc + (size_t)255 * G4_);

    const float* wp = w4s + ((size_t)(kq * 32) * 8 + ((jh_l + kq) & 7)) * 4;

    for (int t = 0; t < TT_; ++t) {
        const float* hin = (t & 1) ? hT1 : hT0;
        float* hout      = (t & 1) ? hT0 : hT1;

        // publish this step's gx slice to LDS
        gx_s[g_lb * 33 + g_g * 8 + g_jl2]     = gxreg.x;
        gx_s[g_lb * 33 + g_g * 8 + g_jl2 + 1] = gxreg.y;
        __syncthreads();     // gx_s ready (covers w4s init on first iter)

        // prefetch next step's gx (latency hides under compute)
        if (t + 1 < TT_)
            gxreg = *(const float2*)(gsrc + (size_t)(TT_ - 2 - t) * G4_);

        // ---- h @ Whh.T over this thread's k-range (32 k, 8 b, 4 gates) ----
        float acc[8][4];
#pragma unroll
        for (int i = 0; i < 8; ++i)
#pragma unroll
            for (int j = 0; j < 4; ++j) acc[i][j] = 0.f;

        const float* hp = hin + (size_t)kq * 32 * 64 + b0 + bq * 8;
#pragma unroll 8
        for (int kk = 0; kk < 32; ++kk) {
            float4 wv = *(const float4*)(wp + (size_t)kk * 32);
            float2 h01 = cohload2(hp + (size_t)kk * 64 + 0);
            float2 h23 = cohload2(hp + (size_t)kk * 64 + 2);
            float2 h45 = cohload2(hp + (size_t)kk * 64 + 4);
            float2 h67 = cohload2(hp + (size_t)kk * 64 + 6);
            float hv[8] = {h01.x, h01.y, h23.x, h23.y, h45.x, h45.y, h67.x, h67.y};
#pragma unroll
            for (int bb = 0; bb < 8; ++bb) {
                acc[bb][0] += hv[bb] * wv.x;
                acc[bb][1] += hv[bb] * wv.y;
                acc[bb][2] += hv[bb] * wv.z;
                acc[bb][3] += hv[bb] * wv.w;
            }
        }

        // ---- butterfly reduce over kq (tid bits 0..3) -> full sum in all lanes ----
#pragma unroll
        for (int m = 1; m <= 8; m <<= 1)
#pragma unroll
            for (int bb = 0; bb < 8; ++bb)
#pragma unroll
                for (int g = 0; g < 4; ++g)
                    acc[bb][g] += __shfl_xor(acc[bb][g], m);

        // ---- gates + state update (lanes kq<8; lane kq owns batch index kq) ----
        float hn = 0.f;
        if (kq < 8) {
            float gi = 0.f, gf = 0.f, gg = 0.f, go = 0.f;
#pragma unroll
            for (int bb = 0; bb < 8; ++bb)
                if (kq == bb) { gi = acc[bb][0]; gf = acc[bb][1];
                                gg = acc[bb][2]; go = acc[bb][3]; }
            int bl = bq * 8 + kq;
            gi += gx_s[bl * 33 + 0 * 8 + jh_l];
            gf += gx_s[bl * 33 + 1 * 8 + jh_l];
            gg += gx_s[bl * 33 + 2 * 8 + jh_l];
            go += gx_s[bl * 33 + 3 * 8 + jh_l];
            float si = 1.f / (1.f + expf(-gi));
            float sf = 1.f / (1.f + expf(-gf));
            float sg = tanhf(gg);
            float so = 1.f / (1.f + expf(-go));
            creg = sf * creg + si * sg;
            hn = so * tanhf(creg);
        }
        // pair (b, b+1) values: lane kq (even) gets lane kq+1's hn
        float hn_up = __shfl_down(hn, 1);
        if (kq < 8 && (kq & 1) == 0) {
            cohstore2(hout + (size_t)jh * 64 + b, hn, hn_up);
            *(float2*)(hsT + ((size_t)t * 512 + jh) * 64 + b) = make_float2(hn, hn_up);
        }

        // ---- distributed grid barrier (relaxed flags, no cache-maintenance) ----
        __syncthreads();   // per-wave vmcnt(0) drain: h stores globally visible (sc1)
        if (tid == 0)
            __hip_atomic_store(&arr[(size_t)blockIdx.x * 32], (unsigned)(t + 1),
                               __ATOMIC_RELAXED, __HIP_MEMORY_SCOPE_AGENT);
        if (tid < 64) {
            unsigned tgt = (unsigned)(t + 1);
            for (;;) {
                bool ok = true;
#pragma unroll
                for (int q = 0; q < 4; ++q)
                    ok &= (__hip_atomic_load(&arr[(size_t)(tid * 4 + q) * 32],
                              __ATOMIC_RELAXED, __HIP_MEMORY_SCOPE_AGENT) >= tgt);
                if (ok) break;
                __builtin_amdgcn_s_sleep(1);
            }
        }
        __syncthreads();
    }
}

// h0 -> transposed [jh][b]
__global__ __launch_bounds__(256) void h0_transpose(
    const float* __restrict__ ah0, float* __restrict__ hT0)
{
    int idx = blockIdx.x * 256 + threadIdx.x;   // 32768
    int b = idx >> 9, jh = idx & 511;
    hT0[jh * 64 + b] = ah0[idx];
}

// score[b][t_orig] = dot(hsT[ts][:][b], Wa) + ba,  ts = T-1-t_orig
__global__ __launch_bounds__(256) void att_scores_T(
    const float* __restrict__ hsT, const float* __restrict__ Wa,
    const float* __restrict__ ba, float* __restrict__ scores)
{
    int ts = blockIdx.x;
    int b = threadIdx.x & 63, part = threadIdx.x >> 6;
    const float* hp = hsT + (size_t)ts * 512 * 64;
    float s = 0.f;
#pragma unroll 8
    for (int jj = 0; jj < 128; ++jj) {
        int jh = part * 128 + jj;
        s += hp[(size_t)jh * 64 + b] * Wa[jh];
    }
    __shared__ float red[4][64];
    red[part][b] = s;
    __syncthreads();
    if (part == 0) {
        float tot = red[0][b] + red[1][b] + red[2][b] + red[3][b] + ba[0];
        scores[b * TT_ + (TT_ - 1 - ts)] = tot;
    }
}

// Per-batch softmax over T, then s[b,d] = sum_t alpha[b,t]*emb[b,t,d].
__global__ __launch_bounds__(256) void softmax_wsum(
    const float* __restrict__ scores, const float* __restrict__ emb,
    float* __restrict__ s)
{
    const int b = blockIdx.x;
    const int tid = threadIdx.x;
    __shared__ float sm[256];
    __shared__ float red[16];
    float v = scores[b * TT_ + tid];
    float m = v;
#pragma unroll
    for (int off = 32; off; off >>= 1) m = fmaxf(m, __shfl_xor(m, off));
    int wv = tid >> 6, ln = tid & 63;
    if (ln == 0) red[wv] = m;
    __syncthreads();
    float bm = fmaxf(fmaxf(red[0], red[1]), fmaxf(red[2], red[3]));
    float e = expf(v - bm);
    float ss = e;
#pragma unroll
    for (int off = 32; off; off >>= 1) ss += __shfl_xor(ss, off);
    if (ln == 0) red[8 + wv] = ss;
    __syncthreads();
    float tot = red[8] + red[9] + red[10] + red[11];
    sm[tid] = e / tot;
    __syncthreads();

    float acc0 = 0.f, acc1 = 0.f;
    const float* ep = emb + (size_t)b * TT_ * DD_;
    for (int t = 0; t < TT_; ++t) {
        float a = sm[t];
        acc0 += a * ep[t * DD_ + tid];
        acc1 += a * ep[t * DD_ + 256 + tid];
    }
    s[b * DD_ + tid] = acc0;
    s[b * DD_ + 256 + tid] = acc1;
}

// beta[b][d] = tanh( sum_jh hTT[jh][b] * Wb[d][jh] + bb )
__global__ __launch_bounds__(256) void beta_from_hT(
    const float* __restrict__ hTT, const float* __restrict__ Wb,
    const float* __restrict__ bbias, float* __restrict__ beta)
{
    int b = threadIdx.x & 63, w = threadIdx.x >> 6;
    int d = blockIdx.x * 4 + w;
    const float* wrow = Wb + (size_t)d * 512;
    float s = 0.f;
#pragma unroll 8
    for (int jh = 0; jh < 512; ++jh)
        s += hTT[(size_t)jh * 64 + b] * wrow[jh];
    beta[(size_t)b * 512 + d] = tanhf(s + bbias[d]);
}

__global__ __launch_bounds__(256) void mulvec(
    const float* __restrict__ a, const float* __restrict__ b,
    float* __restrict__ o, int n)
{
    int i = blockIdx.x * 256 + threadIdx.x;
    if (i < n) o[i] = a[i] * b[i];
}

extern "C" void kernel_launch(void* const* d_in, const int* in_sizes, int n_in,
                              void* d_out, int out_size, void* d_ws, size_t ws_size,
                              hipStream_t stream) {
    const float* x      = (const float*)d_in[0];
    const float* W_emb  = (const float*)d_in[1];
    const float* b_emb  = (const float*)d_in[2];
    const float* Wih_a  = (const float*)d_in[3];
    const float* Whh_a  = (const float*)d_in[4];
    const float* bih_a  = (const float*)d_in[5];
    const float* bhh_a  = (const float*)d_in[6];
    // d_in[7..10]: beta LSTM params — dead code in the reference, skipped.
    const float* W_aatt = (const float*)d_in[11];
    const float* b_aatt = (const float*)d_in[12];
    const float* W_batt = (const float*)d_in[13];
    const float* b_batt = (const float*)d_in[14];
    const float* W_mu   = (const float*)d_in[15];
    const float* b_mu   = (const float*)d_in[16];
    const float* W_sig  = (const float*)d_in[17];
    const float* b_sig  = (const float*)d_in[18];
    const float* ah0    = (const float*)d_in[19];
    const float* ac0    = (const float*)d_in[20];

    const size_t N_EMB = (size_t)BB_ * TT_ * DD_;   // 8,388,608
    const size_t N_GX  = (size_t)BB_ * TT_ * G4_;   // 33,554,432
    const size_t N_HS  = (size_t)TT_ * HH_ * BB_;   // 8,388,608
    const size_t N_BH  = (size_t)BB_ * HH_;         // 32,768
    const size_t N_BAR = 8192;                      // 32 KB barrier region

    size_t need_floats = N_BAR + N_EMB + N_GX + N_HS + 2 * N_BH
                       + (size_t)BB_ * TT_ + 3 * N_BH;
    if (ws_size < need_floats * sizeof(float)) return;

    float* ws     = (float*)d_ws;
    unsigned* arr = (unsigned*)d_ws;                // barrier slots
    float* emb    = ws + N_BAR;
    float* gx     = emb + N_EMB;
    float* hsT    = gx + N_GX;
    float* hT0    = hsT + N_HS;
    float* hT1    = hT0 + N_BH;
    float* scores = hT1 + N_BH;
    float* svec   = scores + (size_t)BB_ * TT_;
    float* beta   = svec + N_BH;
    float* var    = beta + N_BH;

    float* out_mu  = (float*)d_out;
    float* out_sig = out_mu + (size_t)BB_ * ODE_;

    // 0. zero the barrier slots (graph-capturable)
    hipMemsetAsync(d_ws, 0, N_BAR * sizeof(float), stream);

    // 1. h0 -> transposed layout
    h0_transpose<<<dim3(128), dim3(256), 0, stream>>>(ah0, hT0);

    // 2. emb = x @ W_emb.T + b_emb        (M=16384, N=512, K=512)
    gemm_bt<0><<<dim3(DD_ / 128, (BB_ * TT_) / 128), dim3(256), 0, stream>>>(
        x, W_emb, b_emb, nullptr, emb, BB_ * TT_, DD_, DD_, 1.f);

    // 3. gx = emb @ Wih_a.T + bih_a + bhh_a   (M=16384, N=2048, K=512)
    gemm_bt<0><<<dim3(G4_ / 128, (BB_ * TT_) / 128), dim3(256), 0, stream>>>(
        emb, Wih_a, bih_a, bhh_a, gx, BB_ * TT_, G4_, DD_, 1.f);

    // 4. full recurrence in ONE persistent kernel (256 blocks, flag barrier/step)
    lstm_persist<<<dim3(NBLK_), dim3(256), 0, stream>>>(
        gx, Whh_a, ac0, hT0, hT1, hsT, arr);
    // final h lands in hT0 (t=255 writes buffer 0)

    // 5. attention scores
    att_scores_T<<<dim3(TT_), dim3(256), 0, stream>>>(hsT, W_aatt, b_aatt, scores);

    // 6. softmax over T + weighted sum -> svec[b,d]
    softmax_wsum<<<dim3(BB_), dim3(256), 0, stream>>>(scores, emb, svec);

    // 7. beta = tanh(hT @ W_batt.T + b_batt)   (reads transposed hT0)
    beta_from_hT<<<dim3(DD_ / 4), dim3(256), 0, stream>>>(hT0, W_batt, b_batt, beta);

    // 8. var = beta * svec
    mulvec<<<dim3(N_BH / 256), dim3(256), 0, stream>>>(beta, svec, var, (int)N_BH);

    // 9. mu = (var/256) @ W_mu.T + b_mu ; sigma = var @ W_sig.T + b_sig
    gemm_bt<0><<<dim3(ODE_ / 128, 1), dim3(256), 0, stream>>>(
        var, W_mu, b_mu, nullptr, out_mu, BB_, ODE_, DD_, 1.f / 256.f);
    gemm_bt<0><<<dim3(ODE_ / 128, 1), dim3(256), 0, stream>>>(
        var, W_sig, b_sig, nullptr, out_sig, BB_, ODE_, DD_, 1.f);
}

// Round 5
// 2471.131 us; speedup vs baseline: 4.3629x; 2.0882x over previous
//
#include <hip/hip_runtime.h>
#include <hip/hip_bf16.h>
#include <math.h>

#define BB_ 64
#define TT_ 256
#define DD_ 512
#define HH_ 512
#define G4_ 2048
#define ODE_ 256

#define NBLK_ 256   // persistent LSTM grid: 64 j-blocks x 4 b-blocks

// Coherent (cross-XCD) loads/stores: RELAXED AGENT atomics -> sc1 global ops,
// bypass stale per-XCD L2, hit the Infinity Cache coherence point, and emit
// NO cache-wide maintenance (unlike acquire/release).
__device__ __forceinline__ float cohload1(const float* p) {
    unsigned u = __hip_atomic_load((const unsigned*)p,
                                   __ATOMIC_RELAXED, __HIP_MEMORY_SCOPE_AGENT);
    union { unsigned u; float f; } c; c.u = u;
    return c.f;
}
__device__ __forceinline__ void cohstore2(float* p, float a, float b) {
    union { unsigned long long u; float2 f; } c; c.f = make_float2(a, b);
    __hip_atomic_store((unsigned long long*)p, c.u,
                       __ATOMIC_RELAXED, __HIP_MEMORY_SCOPE_AGENT);
}

// ---------------------------------------------------------------------------
// Generic fp32 GEMM:  C[m,n] = act( scale * sum_k A[m,k]*W[n,k] + bias1[n] (+bias2[n]) )
// A: M x K row-major, W: N x K row-major (computes A @ W.T).
// ---------------------------------------------------------------------------
template <int ACT>  // 0 = none, 1 = tanh
__global__ __launch_bounds__(256) void gemm_bt(
    const float* __restrict__ A, const float* __restrict__ W,
    const float* __restrict__ bias1, const float* __restrict__ bias2,
    float* __restrict__ C, int M, int N, int K, float scale)
{
    const int BM = 128, BN = 128, BK = 16;
    __shared__ float As[BK][BM + 4];
    __shared__ float Ws[BK][BN + 4];
    const int tid = threadIdx.x;
    const int tx = tid & 15, ty = tid >> 4;
    const int m0 = blockIdx.y * BM, n0 = blockIdx.x * BN;

    float acc[8][8];
#pragma unroll
    for (int i = 0; i < 8; ++i)
#pragma unroll
        for (int j = 0; j < 8; ++j) acc[i][j] = 0.f;

    for (int k0 = 0; k0 < K; k0 += BK) {
#pragma unroll
        for (int i = 0; i < 2; ++i) {
            int lin = (i * 256 + tid) * 4;
            int r = lin >> 4, c = lin & 15;
            int gm = m0 + r; if (gm > M - 1) gm = M - 1;
            float4 av = *(const float4*)(A + (size_t)gm * K + k0 + c);
            As[c + 0][r] = av.x; As[c + 1][r] = av.y;
            As[c + 2][r] = av.z; As[c + 3][r] = av.w;
            float4 wv = *(const float4*)(W + (size_t)(n0 + r) * K + k0 + c);
            Ws[c + 0][r] = wv.x; Ws[c + 1][r] = wv.y;
            Ws[c + 2][r] = wv.z; Ws[c + 3][r] = wv.w;
        }
        __syncthreads();
#pragma unroll
        for (int k = 0; k < BK; ++k) {
            float a[8], w[8];
#pragma unroll
            for (int i = 0; i < 8; ++i) a[i] = As[k][ty * 8 + i];
#pragma unroll
            for (int j = 0; j < 8; ++j) w[j] = Ws[k][tx * 8 + j];
#pragma unroll
            for (int i = 0; i < 8; ++i)
#pragma unroll
                for (int j = 0; j < 8; ++j) acc[i][j] += a[i] * w[j];
        }
        __syncthreads();
    }

#pragma unroll
    for (int j = 0; j < 8; ++j) {
        int n = n0 + tx * 8 + j;
        float bsum = bias1[n] + (bias2 ? bias2[n] : 0.f);
#pragma unroll
        for (int i = 0; i < 8; ++i) {
            int m = m0 + ty * 8 + i;
            if (m < M) {
                float v = acc[i][j] * scale + bsum;
                if (ACT == 1) v = tanhf(v);
                C[(size_t)m * N + n] = v;
            }
        }
    }
}

// ---------------------------------------------------------------------------
// Persistent LSTM recurrence. 256 blocks x 256 threads (1 block/CU, all CUs).
// Block: jb = blockIdx.x >> 2 (8 jh units), bg = blockIdx.x & 3 (16 batches).
// Thread: kq = tid & 15 (k-interleave: owns k = kk*16+kq), bq = (tid>>4)&1,
//         jh_l = tid >> 5.
// Whh slice in LDS ([k][jl_sw][g], stride 36 -> <=2-way conflicts);
// h staged cooperatively into LDS each step ([k][bl], stride 20, 32 KB, one
// pipelined sc1 load wave -> kills the 8x redundant L3 reads);
// barrier: relaxed fetch_add on 8 spread counters + 8-lane poll (kills the
// 65k-line/round polling flood).
// ---------------------------------------------------------------------------
__global__ __launch_bounds__(256) void lstm_persist(
    const float* __restrict__ gx,     // (B, T, 4H) gate preacts from x (biases included)
    const float* __restrict__ Whh,    // (4H, H)
    const float* __restrict__ ac0,    // (B, H)
    float* __restrict__ hT0,          // (H, B) transposed h, buffer 0 (holds h0 at entry)
    float* __restrict__ hT1,          // (H, B) buffer 1
    float* __restrict__ hsT,          // (T, H, B) transposed per-step h
    unsigned* __restrict__ cnt)       // 8 arrival counters, stride 32 u32 (128B)
{
    __shared__ float w4s[512 * 36];       // [k][jl_sw*4+g] stride 36   (73.7 KB)
    __shared__ float h_s[512 * 20];       // [k][bl]       stride 20   (41.0 KB)
    __shared__ float gx_s[16 * 33];       // [b_local][g*8+jl], padded ( 2.1 KB)

    const int tid = threadIdx.x;
    const int jb = blockIdx.x >> 2;
    const int bg = blockIdx.x & 3;
    const int jh0 = jb * 8;
    const int b0  = bg * 16;
    const int kq   = tid & 15;
    const int bq   = (tid >> 4) & 1;
    const int jh_l = tid >> 5;

    // ---- load Whh slice into LDS once: w4s[k*36 + ((jl + (k&15))&7)*4 + g] ----
#pragma unroll
    for (int it = 0; it < 16; ++it) {
        int idx = it * 256 + tid;            // 0..4095
        int row = idx >> 7;                  // 0..31 = g*8 + jl
        int g = row >> 3, jl = row & 7;
        int c4 = (idx & 127) * 4;            // k base
        float4 v = *(const float4*)(Whh + (size_t)(g * 512 + jh0 + jl) * 512 + c4);
        float vv[4] = {v.x, v.y, v.z, v.w};
#pragma unroll
        for (int i = 0; i < 4; ++i) {
            int k = c4 + i;
            w4s[k * 36 + ((jl + (k & 15)) & 7) * 4 + g] = vv[i];
        }
    }

    // ---- per-thread state: lanes kq<8 own one (b, jh) pair ----
    const int jh = jh0 + jh_l;
    const int b  = b0 + bq * 8 + kq;       // valid when kq < 8
    float creg = 0.f;
    if (kq < 8) creg = ac0[(size_t)b * HH_ + jh];

    // gx stage mapping: thread (lb, g, jl2) loads float2
    const int g_lb  = tid >> 4;            // 0..15 local batch
    const int g_g   = (tid >> 2) & 3;      // gate
    const int g_jl2 = (tid & 3) * 2;       // jl pair
    const float* gsrc = gx + (size_t)(b0 + g_lb) * TT_ * G4_ + g_g * 512 + jh0 + g_jl2;

    // prefetch gx for t = 0 (t_orig = 255)
    float2 gxreg = *(const float2*)(gsrc + (size_t)255 * G4_);

    const int woff = ((jh_l + kq) & 7) * 4;

    for (int t = 0; t < TT_; ++t) {
        const float* hin = (t & 1) ? hT1 : hT0;
        float* hout      = (t & 1) ? hT0 : hT1;

        // publish this step's gx slice to LDS
        gx_s[g_lb * 33 + g_g * 8 + g_jl2]     = gxreg.x;
        gx_s[g_lb * 33 + g_g * 8 + g_jl2 + 1] = gxreg.y;

        // ---- cooperative h stage: 32 KB -> LDS (one pipelined sc1 load wave) ----
        float hstg[32];
#pragma unroll
        for (int j = 0; j < 32; ++j) {
            int idx = j * 256 + tid;
            hstg[j] = cohload1(hin + (size_t)(idx >> 4) * 64 + b0 + (idx & 15));
        }
#pragma unroll
        for (int j = 0; j < 32; ++j) {
            int idx = j * 256 + tid;
            h_s[(idx >> 4) * 20 + (idx & 15)] = hstg[j];
        }
        __syncthreads();     // h_s + gx_s ready (covers w4s init on first iter)

        // prefetch next step's gx (latency hides under compute)
        if (t + 1 < TT_)
            gxreg = *(const float2*)(gsrc + (size_t)(TT_ - 2 - t) * G4_);

        // ---- h @ Whh.T, thread's k = kk*16 + kq (32 k, 8 b, 4 gates) ----
        float acc[8][4];
#pragma unroll
        for (int i = 0; i < 8; ++i)
#pragma unroll
            for (int j = 0; j < 4; ++j) acc[i][j] = 0.f;

#pragma unroll 8
        for (int kk = 0; kk < 32; ++kk) {
            int k = kk * 16 + kq;
            float4 wv = *(const float4*)(w4s + k * 36 + woff);
            float4 ha = *(const float4*)(h_s + k * 20 + bq * 8);
            float4 hb = *(const float4*)(h_s + k * 20 + bq * 8 + 4);
            float hv[8] = {ha.x, ha.y, ha.z, ha.w, hb.x, hb.y, hb.z, hb.w};
#pragma unroll
            for (int bb = 0; bb < 8; ++bb) {
                acc[bb][0] += hv[bb] * wv.x;
                acc[bb][1] += hv[bb] * wv.y;
                acc[bb][2] += hv[bb] * wv.z;
                acc[bb][3] += hv[bb] * wv.w;
            }
        }

        // ---- butterfly reduce over kq (tid bits 0..3) -> full sums in all lanes ----
#pragma unroll
        for (int m = 1; m <= 8; m <<= 1)
#pragma unroll
            for (int bb = 0; bb < 8; ++bb)
#pragma unroll
                for (int g = 0; g < 4; ++g)
                    acc[bb][g] += __shfl_xor(acc[bb][g], m);

        // ---- gates + state update (lanes kq<8; lane kq owns batch b0+bq*8+kq) ----
        float hn = 0.f;
        if (kq < 8) {
            float gi = 0.f, gf = 0.f, gg = 0.f, go = 0.f;
#pragma unroll
            for (int bb = 0; bb < 8; ++bb)
                if (kq == bb) { gi = acc[bb][0]; gf = acc[bb][1];
                                gg = acc[bb][2]; go = acc[bb][3]; }
            int bl = bq * 8 + kq;
            gi += gx_s[bl * 33 + 0 * 8 + jh_l];
            gf += gx_s[bl * 33 + 1 * 8 + jh_l];
            gg += gx_s[bl * 33 + 2 * 8 + jh_l];
            go += gx_s[bl * 33 + 3 * 8 + jh_l];
            float si = 1.f / (1.f + expf(-gi));
            float sf = 1.f / (1.f + expf(-gf));
            float sg = tanhf(gg);
            float so = 1.f / (1.f + expf(-go));
            creg = sf * creg + si * sg;
            hn = so * tanhf(creg);
        }
        // pair (b, b+1) values: even kq lane also gets kq+1's hn
        float hn_up = __shfl_down(hn, 1);
        if (kq < 8 && (kq & 1) == 0) {
            cohstore2(hout + (size_t)jh * 64 + b, hn, hn_up);
            *(float2*)(hsT + ((size_t)t * 512 + jh) * 64 + b) = make_float2(hn, hn_up);
        }

        // ---- hierarchical grid barrier (relaxed; 8 spread counters) ----
        __syncthreads();   // drains vmcnt per wave: h stores acked at L3 before flag
        if (tid == 0)
            __hip_atomic_fetch_add(&cnt[(size_t)(blockIdx.x & 7) * 32], 1u,
                                   __ATOMIC_RELAXED, __HIP_MEMORY_SCOPE_AGENT);
        if (tid < 8) {
            unsigned tgt = (unsigned)(t + 1) * 32u;
            while (__hip_atomic_load(&cnt[(size_t)tid * 32],
                        __ATOMIC_RELAXED, __HIP_MEMORY_SCOPE_AGENT) < tgt)
                __builtin_amdgcn_s_sleep(2);
        }
        __syncthreads();
    }
}

// h0 -> transposed [jh][b]
__global__ __launch_bounds__(256) void h0_transpose(
    const float* __restrict__ ah0, float* __restrict__ hT0)
{
    int idx = blockIdx.x * 256 + threadIdx.x;   // 32768
    int b = idx >> 9, jh = idx & 511;
    hT0[jh * 64 + b] = ah0[idx];
}

// score[b][t_orig] = dot(hsT[ts][:][b], Wa) + ba,  ts = T-1-t_orig
__global__ __launch_bounds__(256) void att_scores_T(
    const float* __restrict__ hsT, const float* __restrict__ Wa,
    const float* __restrict__ ba, float* __restrict__ scores)
{
    int ts = blockIdx.x;
    int b = threadIdx.x & 63, part = threadIdx.x >> 6;
    const float* hp = hsT + (size_t)ts * 512 * 64;
    float s = 0.f;
#pragma unroll 8
    for (int jj = 0; jj < 128; ++jj) {
        int jh = part * 128 + jj;
        s += hp[(size_t)jh * 64 + b] * Wa[jh];
    }
    __shared__ float red[4][64];
    red[part][b] = s;
    __syncthreads();
    if (part == 0) {
        float tot = red[0][b] + red[1][b] + red[2][b] + red[3][b] + ba[0];
        scores[b * TT_ + (TT_ - 1 - ts)] = tot;
    }
}

// Per-batch softmax over T, then s[b,d] = sum_t alpha[b,t]*emb[b,t,d].
__global__ __launch_bounds__(256) void softmax_wsum(
    const float* __restrict__ scores, const float* __restrict__ emb,
    float* __restrict__ s)
{
    const int b = blockIdx.x;
    const int tid = threadIdx.x;
    __shared__ float sm[256];
    __shared__ float red[16];
    float v = scores[b * TT_ + tid];
    float m = v;
#pragma unroll
    for (int off = 32; off; off >>= 1) m = fmaxf(m, __shfl_xor(m, off));
    int wv = tid >> 6, ln = tid & 63;
    if (ln == 0) red[wv] = m;
    __syncthreads();
    float bm = fmaxf(fmaxf(red[0], red[1]), fmaxf(red[2], red[3]));
    float e = expf(v - bm);
    float ss = e;
#pragma unroll
    for (int off = 32; off; off >>= 1) ss += __shfl_xor(ss, off);
    if (ln == 0) red[8 + wv] = ss;
    __syncthreads();
    float tot = red[8] + red[9] + red[10] + red[11];
    sm[tid] = e / tot;
    __syncthreads();

    float acc0 = 0.f, acc1 = 0.f;
    const float* ep = emb + (size_t)b * TT_ * DD_;
    for (int t = 0; t < TT_; ++t) {
        float a = sm[t];
        acc0 += a * ep[t * DD_ + tid];
        acc1 += a * ep[t * DD_ + 256 + tid];
    }
    s[b * DD_ + tid] = acc0;
    s[b * DD_ + 256 + tid] = acc1;
}

// beta[b][d] = tanh( sum_jh hTT[jh][b] * Wb[d][jh] + bb )
__global__ __launch_bounds__(256) void beta_from_hT(
    const float* __restrict__ hTT, const float* __restrict__ Wb,
    const float* __restrict__ bbias, float* __restrict__ beta)
{
    int b = threadIdx.x & 63, w = threadIdx.x >> 6;
    int d = blockIdx.x * 4 + w;
    const float* wrow = Wb + (size_t)d * 512;
    float s = 0.f;
#pragma unroll 8
    for (int jh = 0; jh < 512; ++jh)
        s += hTT[(size_t)jh * 64 + b] * wrow[jh];
    beta[(size_t)b * 512 + d] = tanhf(s + bbias[d]);
}

__global__ __launch_bounds__(256) void mulvec(
    const float* __restrict__ a, const float* __restrict__ b,
    float* __restrict__ o, int n)
{
    int i = blockIdx.x * 256 + threadIdx.x;
    if (i < n) o[i] = a[i] * b[i];
}

extern "C" void kernel_launch(void* const* d_in, const int* in_sizes, int n_in,
                              void* d_out, int out_size, void* d_ws, size_t ws_size,
                              hipStream_t stream) {
    const float* x      = (const float*)d_in[0];
    const float* W_emb  = (const float*)d_in[1];
    const float* b_emb  = (const float*)d_in[2];
    const float* Wih_a  = (const float*)d_in[3];
    const float* Whh_a  = (const float*)d_in[4];
    const float* bih_a  = (const float*)d_in[5];
    const float* bhh_a  = (const float*)d_in[6];
    // d_in[7..10]: beta LSTM params — dead code in the reference, skipped.
    const float* W_aatt = (const float*)d_in[11];
    const float* b_aatt = (const float*)d_in[12];
    const float* W_batt = (const float*)d_in[13];
    const float* b_batt = (const float*)d_in[14];
    const float* W_mu   = (const float*)d_in[15];
    const float* b_mu   = (const float*)d_in[16];
    const float* W_sig  = (const float*)d_in[17];
    const float* b_sig  = (const float*)d_in[18];
    const float* ah0    = (const float*)d_in[19];
    const float* ac0    = (const float*)d_in[20];

    const size_t N_EMB = (size_t)BB_ * TT_ * DD_;   // 8,388,608
    const size_t N_GX  = (size_t)BB_ * TT_ * G4_;   // 33,554,432
    const size_t N_HS  = (size_t)TT_ * HH_ * BB_;   // 8,388,608
    const size_t N_BH  = (size_t)BB_ * HH_;         // 32,768
    const size_t N_BAR = 8192;                      // 32 KB barrier region

    size_t need_floats = N_BAR + N_EMB + N_GX + N_HS + 2 * N_BH
                       + (size_t)BB_ * TT_ + 3 * N_BH;
    if (ws_size < need_floats * sizeof(float)) return;

    float* ws     = (float*)d_ws;
    unsigned* cnt = (unsigned*)d_ws;                // 8 counters, 128B apart
    float* emb    = ws + N_BAR;
    float* gx     = emb + N_EMB;
    float* hsT    = gx + N_GX;
    float* hT0    = hsT + N_HS;
    float* hT1    = hT0 + N_BH;
    float* scores = hT1 + N_BH;
    float* svec   = scores + (size_t)BB_ * TT_;
    float* beta   = svec + N_BH;
    float* var    = beta + N_BH;

    float* out_mu  = (float*)d_out;
    float* out_sig = out_mu + (size_t)BB_ * ODE_;

    // 0. zero the barrier counters (graph-capturable)
    hipMemsetAsync(d_ws, 0, N_BAR * sizeof(float), stream);

    // 1. h0 -> transposed layout
    h0_transpose<<<dim3(128), dim3(256), 0, stream>>>(ah0, hT0);

    // 2. emb = x @ W_emb.T + b_emb        (M=16384, N=512, K=512)
    gemm_bt<0><<<dim3(DD_ / 128, (BB_ * TT_) / 128), dim3(256), 0, stream>>>(
        x, W_emb, b_emb, nullptr, emb, BB_ * TT_, DD_, DD_, 1.f);

    // 3. gx = emb @ Wih_a.T + bih_a + bhh_a   (M=16384, N=2048, K=512)
    gemm_bt<0><<<dim3(G4_ / 128, (BB_ * TT_) / 128), dim3(256), 0, stream>>>(
        emb, Wih_a, bih_a, bhh_a, gx, BB_ * TT_, G4_, DD_, 1.f);

    // 4. full recurrence in ONE persistent kernel (256 blocks, flag barrier/step)
    lstm_persist<<<dim3(NBLK_), dim3(256), 0, stream>>>(
        gx, Whh_a, ac0, hT0, hT1, hsT, cnt);
    // final h lands in hT0 (t=255 writes buffer 0)

    // 5. attention scores
    att_scores_T<<<dim3(TT_), dim3(256), 0, stream>>>(hsT, W_aatt, b_aatt, scores);

    // 6. softmax over T + weighted sum -> svec[b,d]
    softmax_wsum<<<dim3(BB_), dim3(256), 0, stream>>>(scores, emb, svec);

    // 7. beta = tanh(hT @ W_batt.T + b_batt)   (reads transposed hT0)
    beta_from_hT<<<dim3(DD_ / 4), dim3(256), 0, stream>>>(hT0, W_batt, b_batt, beta);

    // 8. var = beta * svec
    mulvec<<<dim3(N_BH / 256), dim3(256), 0, stream>>>(beta, svec, var, (int)N_BH);

    // 9. mu = (var/256) @ W_mu.T + b_mu ; sigma = var @ W_sig.T + b_sig
    gemm_bt<0><<<dim3(ODE_ / 128, 1), dim3(256), 0, stream>>>(
        var, W_mu, b_mu, nullptr, out_mu, BB_, ODE_, DD_, 1.f / 256.f);
    gemm_bt<0><<<dim3(ODE_ / 128, 1), dim3(256), 0, stream>>>(
        var, W_sig, b_sig, nullptr, out_sig, BB_, ODE_, DD_, 1.f);
}